// Round 1
// baseline (86.970 us; speedup 1.0000x reference)
//
#include <hip/hip_runtime.h>
#include <hip/hip_fp8.h>

// Problem constants (from reference)
#define S_CNT 4096
#define D_DIM 8
#define N_CNT 16384
#define E_CNT (1 << 20)

// Pair term tiling
#define QT 128
#define NTILE (S_CNT / QT)                   // 32
#define PAIR_BLK (NTILE * (NTILE + 1) / 2)   // 528 triangular tile-pairs

// Edge term: 256 blocks (1/CU) x 512 thr x 8 edges = 2^20
#define EDGE_BLK_N 256
#define EDGE_THR 512
#define EDGE_WAVES (EDGE_THR / 64)           // 8
#define EDGE_PART (EDGE_BLK_N * EDGE_WAVES)  // 2048 per-wave partials
#define TOT_PART (PAIR_BLK + EDGE_PART)      // 2576

// Edge kernel LDS: fp8 Z table (8B/node) + bf16 beta table (2B/node)
#define EDGE_LDS_Z (N_CNT * 8)               // 131072
#define EDGE_LDS_B (N_CNT * 2)               // 32768
#define EDGE_LDS   (EDGE_LDS_Z + EDGE_LDS_B) // 163840 = 160 KiB (full CU)

// ws layout (bytes): part[2576] f32 @ 0 ; tz uint2[16384] @ 16K ;
//   tb u16[16384] @ 147456 ; bs f32[4096] @ 180224 ; Zs f32[4096*8] @ 196608
#define WS_TZ_OFF (16 * 1024)
#define WS_TB_OFF (WS_TZ_OFF + EDGE_LDS_Z)
#define WS_BS_OFF (WS_TB_OFF + EDGE_LDS_B)
#define WS_ZS_OFF (WS_BS_OFF + S_CNT * 4)

__device__ __forceinline__ unsigned int pack4_fp8(float4 v) {
    __hip_fp8_e4m3 a(v.x), b(v.y), c(v.z), d(v.w);
    return (unsigned int)a.__x | ((unsigned int)b.__x << 8)
         | ((unsigned int)c.__x << 16) | ((unsigned int)d.__x << 24);
}

__device__ __forceinline__ float fp8f(unsigned int u, int byte) {
    __hip_fp8_e4m3 t;
    t.__x = (unsigned char)(u >> (byte * 8));
    return (float)t;
}

__device__ __forceinline__ unsigned short f2bf(float f) {
    // round-to-nearest-even bf16 truncation (beta is always a normal float)
    unsigned u = __float_as_uint(f);
    return (unsigned short)((u + 0x7FFFu + ((u >> 16) & 1u)) >> 16);
}

__device__ __forceinline__ float bf16f(unsigned short u) {
    return __uint_as_float(((unsigned int)u) << 16);
}

// Block-level sum over 4 waves; full total valid on thread 0.
__device__ __forceinline__ float block_reduce(float v) {
    #pragma unroll
    for (int off = 32; off > 0; off >>= 1)
        v += __shfl_down(v, off, 64);
    __shared__ float wsum[4];
    const int lane = threadIdx.x & 63;
    const int wid  = threadIdx.x >> 6;
    if (lane == 0) wsum[wid] = v;
    __syncthreads();
    return (wsum[0] + wsum[1]) + (wsum[2] + wsum[3]);
}

// Prep: blocks 0..63 pack per-node records (fp8 Z -> uint2, bf16 beta);
//       blocks 64..79 gather the sampled compact f32 arrays bs/Zs (exact).
__global__ __launch_bounds__(256) void lsm_prep_kernel(
        const float* __restrict__ beta, const float* __restrict__ Z,
        const int* __restrict__ sidx, uint2* __restrict__ tz,
        unsigned short* __restrict__ tb, float* __restrict__ bs,
        float* __restrict__ Zs) {
    const int b = blockIdx.x;
    const int tid = threadIdx.x;
    if (b < 64) {
        const int n = b * 256 + tid;                 // [0, 16384)
        const float4* zr = (const float4*)(Z + (size_t)n * D_DIM);
        const float4 z0 = zr[0], z1 = zr[1];
        uint2 rec;
        rec.x = pack4_fp8(z0);
        rec.y = pack4_fp8(z1);
        tz[n] = rec;
        tb[n] = f2bf(beta[n]);
    } else {
        const int s = (b - 64) * 256 + tid;          // [0, 4096)
        const int idx = sidx[s];
        bs[s] = beta[idx];
        const float4* zr = (const float4*)(Z + (size_t)idx * D_DIM);
        float4* zo = (float4*)(Zs + (size_t)s * D_DIM);
        zo[0] = zr[0];
        zo[1] = zr[1];
    }
}

// Pair term over compact f32 arrays. Small static LDS -> multi-block/CU.
// Writes NEGATED partial to part[blockIdx.x].
__global__ __launch_bounds__(256) void lsm_pair_kernel(
        const float* __restrict__ bs, const float* __restrict__ Zs,
        float* __restrict__ part) {
    const int tid = threadIdx.x;

    int k = blockIdx.x;
    int I = (int)((__builtin_sqrtf(8.f * (float)k + 1.f) - 1.f) * 0.5f);
    while ((I + 1) * (I + 2) / 2 <= k) ++I;
    while (I * (I + 1) / 2 > k) --I;
    const int J = k - I * (I + 1) / 2;

    __shared__ float4 sZ0[QT];
    __shared__ float4 sZ1[QT];
    __shared__ float2 sM[QT];   // (b_q, |Z_q|^2)

    if (tid < QT) {
        const int q = J * QT + tid;
        const float4* zr = (const float4*)(Zs + (size_t)q * D_DIM);
        float4 z0 = zr[0], z1 = zr[1];
        float nq = z0.x * z0.x + z0.y * z0.y + z0.z * z0.z + z0.w * z0.w
                 + z1.x * z1.x + z1.y * z1.y + z1.z * z1.z + z1.w * z1.w;
        sZ0[tid] = z0;
        sZ1[tid] = z1;
        sM[tid]  = make_float2(bs[q], nq);
    }

    const int pl = tid & (QT - 1);
    const int pg = I * QT + pl;           // global p (sample index)
    const float4* zp4 = (const float4*)(Zs + (size_t)pg * D_DIM);
    const float4 a0 = zp4[0], a1 = zp4[1];
    const float bp = bs[pg];
    const float np = a0.x * a0.x + a0.y * a0.y + a0.z * a0.z + a0.w * a0.w
                   + a1.x * a1.x + a1.y * a1.y + a1.z * a1.z + a1.w * a1.w;
    __syncthreads();

    const int qh = tid >> 7;              // 0 or 1: which 64-q half
    const int ql0 = qh * 64;
    const int qg0 = J * QT + ql0;

    float acc = 0.f;
    #pragma unroll 4
    for (int qq = 0; qq < 64; ++qq) {
        const int ql = ql0 + qq;
        const float4 b0 = sZ0[ql];
        const float4 b1 = sZ1[ql];
        const float2 m  = sM[ql];
        float dot = a0.x * b0.x;
        dot = __builtin_fmaf(a0.y, b0.y, dot);
        dot = __builtin_fmaf(a0.z, b0.z, dot);
        dot = __builtin_fmaf(a0.w, b0.w, dot);
        dot = __builtin_fmaf(a1.x, b1.x, dot);
        dot = __builtin_fmaf(a1.y, b1.y, dot);
        dot = __builtin_fmaf(a1.z, b1.z, dot);
        dot = __builtin_fmaf(a1.w, b1.w, dot);
        float d2 = __builtin_fmaf(-2.f, dot, np + m.y);
        d2 = fmaxf(d2, 0.f);              // guard cancellation-negative
        const float dist = __builtin_sqrtf(d2);
        const float e = __expf(bp + m.x - dist);
        acc += (qg0 + qq < pg) ? e : 0.f; // strict lower triangle only
    }

    const float tot = block_reduce(-acc); // pair term enters negatively
    if (tid == 0) part[blockIdx.x] = tot;
}

// Edge term: full node table resident in LDS (160 KiB dynamic -> 1 block/CU).
// All 2M random lookups become ds_read_b64/ds_read_u16 instead of divergent
// global gathers (the previous request-rate bottleneck).
// NOTE: no static __shared__ allowed here (160 KiB dynamic is the whole CU);
// reduction is per-wave shuffle only -> part[blk*8 + wave].
__global__ __launch_bounds__(EDGE_THR) void lsm_edge_kernel(
        const uint2* __restrict__ tz, const unsigned short* __restrict__ tb,
        const int* __restrict__ si, const int* __restrict__ sj,
        float* __restrict__ part) {
    extern __shared__ char smem[];
    const uint2* lz = (const uint2*)smem;
    const unsigned short* lb = (const unsigned short*)(smem + EDGE_LDS_Z);

    const int tid = threadIdx.x;
    const int gid = blockIdx.x * EDGE_THR + tid;     // [0, 131072)
    const int4* si4 = (const int4*)si;
    const int4* sj4 = (const int4*)sj;

    // Issue the HBM index loads first so their latency hides under staging.
    int4 vi[2], vj[2];
    #pragma unroll
    for (int c = 0; c < 2; ++c) {
        vi[c] = si4[gid + c * (EDGE_BLK_N * EDGE_THR / 2) * 1];
        vj[c] = sj4[gid + c * (EDGE_BLK_N * EDGE_THR / 2) * 1];
    }

    // Stage both tables into LDS with coalesced uint4 copies.
    {
        const uint4* gz4 = (const uint4*)tz;         // 8192 uint4
        uint4* lz4 = (uint4*)smem;
        #pragma unroll
        for (int c = 0; c < 16; ++c)                 // 16 * 512 = 8192
            lz4[tid + c * EDGE_THR] = gz4[tid + c * EDGE_THR];
        const uint4* gb4 = (const uint4*)tb;         // 2048 uint4
        uint4* lb4 = (uint4*)(smem + EDGE_LDS_Z);
        #pragma unroll
        for (int c = 0; c < 4; ++c)                  //  4 * 512 = 2048
            lb4[tid + c * EDGE_THR] = gb4[tid + c * EDGE_THR];
    }
    __syncthreads();

    float acc = 0.f;
    #pragma unroll
    for (int c = 0; c < 2; ++c) {
        const int is[4] = {vi[c].x, vi[c].y, vi[c].z, vi[c].w};
        const int js[4] = {vj[c].x, vj[c].y, vj[c].z, vj[c].w};

        uint2 ri[4], rj[4];
        float bsum[4];
        #pragma unroll
        for (int e = 0; e < 4; ++e) {
            ri[e] = lz[is[e]];
            rj[e] = lz[js[e]];
            bsum[e] = bf16f(lb[is[e]]) + bf16f(lb[js[e]]);
        }
        #pragma unroll
        for (int e = 0; e < 4; ++e) {
            float d2 = 0.f;
            #pragma unroll
            for (int by = 0; by < 4; ++by) {
                float u = fp8f(ri[e].x, by) - fp8f(rj[e].x, by);
                d2 = __builtin_fmaf(u, u, d2);
                float v = fp8f(ri[e].y, by) - fp8f(rj[e].y, by);
                d2 = __builtin_fmaf(v, v, d2);
            }
            acc += bsum[e] - __builtin_sqrtf(d2);
        }
    }

    // Per-wave shuffle reduction; lane 0 of each wave stores its partial.
    #pragma unroll
    for (int off = 32; off > 0; off >>= 1)
        acc += __shfl_down(acc, off, 64);
    if ((tid & 63) == 0)
        part[blockIdx.x * EDGE_WAVES + (tid >> 6)] = acc;
}

// Finish: one block sums all TOT_PART partials.
__global__ __launch_bounds__(256) void lsm_finish_kernel(
        const float* __restrict__ part, float* __restrict__ out) {
    const int tid = threadIdx.x;
    float v = 0.f;
    #pragma unroll
    for (int c = 0; c < 11; ++c) {                   // 11*256 = 2816 >= 2576
        const int t = tid + c * 256;
        if (t < TOT_PART) v += part[t];
    }
    const float tot = block_reduce(v);
    if (tid == 0) out[0] = tot;
}

extern "C" void kernel_launch(void* const* d_in, const int* in_sizes, int n_in,
                              void* d_out, int out_size, void* d_ws, size_t ws_size,
                              hipStream_t stream) {
    const float* beta = (const float*)d_in[0];
    const float* Z    = (const float*)d_in[1];
    const int*   sidx = (const int*)d_in[2];
    const int*   si   = (const int*)d_in[3];
    const int*   sj   = (const int*)d_in[4];
    float* out = (float*)d_out;

    char* ws = (char*)d_ws;
    float*          part = (float*)ws;
    uint2*          tz   = (uint2*)(ws + WS_TZ_OFF);
    unsigned short* tb   = (unsigned short*)(ws + WS_TB_OFF);
    float*          bs   = (float*)(ws + WS_BS_OFF);
    float*          Zs   = (float*)(ws + WS_ZS_OFF);

    // One-time opt-in for 160 KiB dynamic LDS (host-side, graph-capture safe).
    static int attr_set = 0;
    if (!attr_set) {
        hipFuncSetAttribute((const void*)lsm_edge_kernel,
                            hipFuncAttributeMaxDynamicSharedMemorySize,
                            EDGE_LDS);
        attr_set = 1;
    }

    lsm_prep_kernel<<<80, 256, 0, stream>>>(beta, Z, sidx, tz, tb, bs, Zs);
    lsm_pair_kernel<<<PAIR_BLK, 256, 0, stream>>>(bs, Zs, part);
    lsm_edge_kernel<<<EDGE_BLK_N, EDGE_THR, EDGE_LDS, stream>>>(
        tz, tb, si, sj, part + PAIR_BLK);
    lsm_finish_kernel<<<1, 256, 0, stream>>>(part, out);
}